// Round 7
// baseline (17.221 us; speedup 1.0000x reference)
//
#include <hip/hip_runtime.h>
#include <math.h>

// ESPRIT DOA: only frames 120..123, bins 13..31, 4 mics are consumed by the
// reference. Multi-CU version: one workgroup per frequency bin (19 WGs),
// one wave per frame. Cross-WG combine via last-block atomic pattern in d_ws.
// x is (T, 4) row-major float -> one sample (4 mics) == one float4.

#define KLO    13
#define NK     19        // bins 13..31  (400 <= f < 1000, f = k*31.25)
#define XBASE  30464     // T_START*HOP - NFFT/2
#define PI_F   3.14159265358979f

struct cf { float x, y; };
__device__ inline cf cadd(cf a, cf b){ return {a.x+b.x, a.y+b.y}; }
__device__ inline cf csub(cf a, cf b){ return {a.x-b.x, a.y-b.y}; }
__device__ inline cf cmul(cf a, cf b){ return {a.x*b.x - a.y*b.y, a.x*b.y + a.y*b.x}; }
__device__ inline cf cmulc(cf a, cf b){ return {a.x*b.x + a.y*b.y, a.y*b.x - a.x*b.y}; } // a*conj(b)
__device__ inline cf cscale(cf a, float s){ return {a.x*s, a.y*s}; }
__device__ inline cf csqrtf_c(cf z){
    float r = sqrtf(z.x*z.x + z.y*z.y);
    float u = sqrtf(fmaxf(0.5f*(r + z.x), 0.0f));
    float v = sqrtf(fmaxf(0.5f*(r - z.x), 0.0f));
    if (z.y < 0.0f) v = -v;
    return {u, v};
}

__global__ __launch_bounds__(256)
void esprit_multi(const float* __restrict__ x, float* __restrict__ out,
                  unsigned* __restrict__ counter, float* __restrict__ angles)
{
    __shared__ float XsR[4][4], XsI[4][4];   // [frame][mic]

    const int tid  = threadIdx.x;
    const int lane = tid & 63;
    const int t    = tid >> 6;               // wave = frame 0..3
    const int b    = blockIdx.x;             // bin index 0..18
    const int k    = KLO + b;

    // ---- windowed DFT of frame t at bin k; 8 samples/lane, stride 64 ------
    // n = lane + 64*j ; loads are fully coalesced (64 consecutive float4).
    const float4* __restrict__ xp = (const float4*)x + (XBASE + (t << 8));
    float4 v0 = xp[lane];        float4 v1 = xp[lane +  64];
    float4 v2 = xp[lane + 128];  float4 v3 = xp[lane + 192];
    float4 v4 = xp[lane + 256];  float4 v5 = xp[lane + 320];
    float4 v6 = xp[lane + 384];  float4 v7 = xp[lane + 448];

    const int j0 = (k * lane) & 511;         // exact k*n mod 512 at j=0
    float cr, ci;
    __sincosf((float)j0 * (-2.0f * PI_F / 512.0f), &ci, &cr);  // e^{-2pi i j0/512}
    const int j1 = (k << 6) & 511;           // step: 64k mod 512
    float wc, ws;
    __sincosf((float)j1 * (-2.0f * PI_F / 512.0f), &ws, &wc);  // e^{-2pi i j1/512}
    float hs, hc;
    __sincosf((float)lane * (PI_F / 512.0f), &hs, &hc);        // window sin/cos
    const float c8 = 0.9238795325112867f, s8 = 0.3826834323650898f; // pi/8 step

    float re0=0,re1=0,re2=0,re3=0, im0=0,im1=0,im2=0,im3=0;
    float4 vv[8] = {v0,v1,v2,v3,v4,v5,v6,v7};
    #pragma unroll
    for (int j = 0; j < 8; ++j) {
        float4 v = vv[j];
        float a = hs * cr, bb = hs * ci;     // window folded into twiddle
        re0 = fmaf(v.x, a, re0); im0 = fmaf(v.x, bb, im0);
        re1 = fmaf(v.y, a, re1); im1 = fmaf(v.y, bb, im1);
        re2 = fmaf(v.z, a, re2); im2 = fmaf(v.z, bb, im2);
        re3 = fmaf(v.w, a, re3); im3 = fmaf(v.w, bb, im3);
        // rotate twiddle by e^{-2pi i 64k/512}
        float nr = fmaf(cr, wc, -(ci * ws));
        float ni = fmaf(cr, ws,  (ci * wc));
        cr = nr; ci = ni;
        // rotate window phase by +pi/8: sin/cos angle addition
        float nhs = fmaf(hs, c8,  (hc * s8));
        float nhc = fmaf(hc, c8, -(hs * s8));
        hs = nhs; hc = nhc;
    }
    // full-wave butterfly reduce (64 lanes)
    #pragma unroll
    for (int mask = 1; mask < 64; mask <<= 1) {
        re0 += __shfl_xor(re0, mask); im0 += __shfl_xor(im0, mask);
        re1 += __shfl_xor(re1, mask); im1 += __shfl_xor(im1, mask);
        re2 += __shfl_xor(re2, mask); im2 += __shfl_xor(im2, mask);
        re3 += __shfl_xor(re3, mask); im3 += __shfl_xor(im3, mask);
    }
    if (lane == 0) {
        XsR[t][0] = re0; XsI[t][0] = im0;
        XsR[t][1] = re1; XsI[t][1] = im1;
        XsR[t][2] = re2; XsI[t][2] = im2;
        XsR[t][3] = re3; XsI[t][3] = im3;
    }
    __syncthreads();

    // ---- ESPRIT for this bin (wave 0, all lanes redundant) ----------------
    if (t == 0) {
        cf Xm[4][4];   // [mic][frame] — broadcast LDS reads
        #pragma unroll
        for (int m = 0; m < 4; ++m)
            #pragma unroll
            for (int tt = 0; tt < 4; ++tt)
                Xm[m][tt] = { XsR[tt][m], XsI[tt][m] };

        // R = (1/4) Xs Xs^H
        cf R[4][4];
        for (int i = 0; i < 4; ++i)
            for (int j = 0; j < 4; ++j) {
                cf acc = {0.f, 0.f};
                for (int tt = 0; tt < 4; ++tt) acc = cadd(acc, cmulc(Xm[i][tt], Xm[j][tt]));
                R[i][j] = cscale(acc, 0.25f);
            }

        // one orthogonal-iteration step -> dominant 2-D subspace
        // (phi eigvals similarity-invariant; lam3/lam2 ~ 1e-8 at -80 dB noise)
        cf Q[4][2], Y[4][2];
        for (int i = 0; i < 4; ++i) { Y[i][0] = R[i][0]; Y[i][1] = R[i][1]; }
        float nrm0 = 0.f;
        for (int i = 0; i < 4; ++i) nrm0 += Y[i][0].x*Y[i][0].x + Y[i][0].y*Y[i][0].y;
        float in0 = __builtin_amdgcn_rsqf(nrm0);
        for (int i = 0; i < 4; ++i) Q[i][0] = cscale(Y[i][0], in0);
        cf pr = {0.f, 0.f};
        for (int i = 0; i < 4; ++i) pr = cadd(pr, cmulc(Y[i][1], Q[i][0]));  // Q0^H Y1
        for (int i = 0; i < 4; ++i) Q[i][1] = csub(Y[i][1], cmul(pr, Q[i][0]));
        float nrm1 = 0.f;
        for (int i = 0; i < 4; ++i) nrm1 += Q[i][1].x*Q[i][1].x + Q[i][1].y*Q[i][1].y;
        float in1 = __builtin_amdgcn_rsqf(nrm1);
        for (int i = 0; i < 4; ++i) Q[i][1] = cscale(Q[i][1], in1);

        // A = s0^H s0 (Hermitian), B = s0^H s1 ; s0 = rows 0..2, s1 = rows 1..3
        float a00 = 0.f, a11 = 0.f;
        cf a01 = {0.f, 0.f};
        cf B[2][2] = { { {0,0}, {0,0} }, { {0,0}, {0,0} } };
        for (int i = 0; i < 3; ++i) {
            a00 += Q[i][0].x*Q[i][0].x + Q[i][0].y*Q[i][0].y;
            a11 += Q[i][1].x*Q[i][1].x + Q[i][1].y*Q[i][1].y;
            a01 = cadd(a01, cmulc(Q[i][1], Q[i][0]));      // conj(Q0)*Q1
            for (int r2 = 0; r2 < 2; ++r2)
                for (int c2 = 0; c2 < 2; ++c2)
                    B[r2][c2] = cadd(B[r2][c2], cmulc(Q[i+1][c2], Q[i][r2]));
        }
        float detA = a00*a11 - (a01.x*a01.x + a01.y*a01.y);
        float inv  = __builtin_amdgcn_rcpf(detA);
        cf na01  = { -a01.x, -a01.y };
        cf na01c = { -a01.x,  a01.y };
        cf phi00 = cscale(cadd(cscale(B[0][0], a11), cmul(na01,  B[1][0])), inv);
        cf phi01 = cscale(cadd(cscale(B[0][1], a11), cmul(na01,  B[1][1])), inv);
        cf phi10 = cscale(cadd(cmul(na01c, B[0][0]), cscale(B[1][0], a00)), inv);
        cf phi11 = cscale(cadd(cmul(na01c, B[0][1]), cscale(B[1][1], a00)), inv);

        cf tr = cadd(phi00, phi11);
        cf dt = csub(cmul(phi00, phi11), cmul(phi01, phi10));
        cf d2 = csub(cmul(tr, tr), cscale(dt, 4.0f));
        cf disc = csqrtf_c(d2);
        cf lam0 = cscale(cadd(tr, disc), 0.5f);
        cf lam1 = cscale(csub(tr, disc), 0.5f);

        float f     = 31.25f * (float)k;
        float scale = 343.0f / (2.0f * PI_F * f * 0.08f);
        float ph0 = atan2f(lam0.y, lam0.x);
        float ph1 = atan2f(lam1.y, lam1.x);
        float g0 = fminf(fmaxf(ph0 * scale, -1.0f), 1.0f);
        float g1 = fminf(fmaxf(ph1 * scale, -1.0f), 1.0f);
        float ang = (asinf(g0) + asinf(g1)) * (180.0f / PI_F);

        // ---- last-block combine (agent-scope atomics; no spin-waits) ------
        if (lane == 0) {
            __hip_atomic_store(&angles[b], ang, __ATOMIC_RELEASE,
                               __HIP_MEMORY_SCOPE_AGENT);
            unsigned old = __hip_atomic_fetch_add(counter, 1u, __ATOMIC_ACQ_REL,
                                                  __HIP_MEMORY_SCOPE_AGENT);
            if (old == NK - 1) {
                float s = 0.f;
                for (int i = 0; i < NK; ++i)
                    s += __hip_atomic_load(&angles[i], __ATOMIC_ACQUIRE,
                                           __HIP_MEMORY_SCOPE_AGENT);
                out[0] = s * (1.0f / 38.0f);
            }
        }
    }
}

extern "C" void kernel_launch(void* const* d_in, const int* in_sizes, int n_in,
                              void* d_out, int out_size, void* d_ws, size_t ws_size,
                              hipStream_t stream)
{
    const float* x   = (const float*)d_in[0];
    float* out       = (float*)d_out;
    unsigned* counter = (unsigned*)d_ws;                       // 4 bytes
    float* angles     = (float*)((char*)d_ws + 256);           // 19 floats

    // zero the arrival counter every call (graph-capturable, deterministic)
    hipMemsetAsync(counter, 0, sizeof(unsigned), stream);
    esprit_multi<<<NK, 256, 0, stream>>>(x, out, counter, angles);
}

// Round 8
// 11.417 us; speedup vs baseline: 1.5083x; 1.5083x over previous
//
#include <hip/hip_runtime.h>
#include <math.h>

// ESPRIT DOA: only frames 120..123, bins 13..31, 4 mics are consumed by the
// reference. Single workgroup, two barriers, all-float latency pipeline.
// x is (T, 4) row-major float -> one sample (4 mics) == one float4.
// Structure = round-4 (measured best, 12.8 us); stage-2 chain shortened.

#define NFFT   512
#define KLO    13
#define NK     19        // bins 13..31  (400 <= f < 1000, f = k*31.25)
#define NTT    4         // frames 120..123
#define NMIC   4
#define XBASE  30464     // T_START*HOP - NFFT/2
#define PI_F   3.14159265358979f

// xw LDS layout (pre-windowed frames, float, mic-interleaved, skewed):
//   phys(t,n) = t*2084 + (n>>6)*260 + (n&63)*4      (dword units, 16B-aligned)
// frame stride 2084 and chunk stride 260 are ≡4 (mod 32) so per-lane
// ds_read_b128 bank-groups spread instead of stacking.
#define FRM_STRIDE 2084
#define CHK_STRIDE 260
#define XW_SIZE    8328

struct cf { float x, y; };
__device__ inline cf cadd(cf a, cf b){ return {a.x+b.x, a.y+b.y}; }
__device__ inline cf csub(cf a, cf b){ return {a.x-b.x, a.y-b.y}; }
__device__ inline cf cmul(cf a, cf b){ return {a.x*b.x - a.y*b.y, a.x*b.y + a.y*b.x}; }
__device__ inline cf cmulc(cf a, cf b){ return {a.x*b.x + a.y*b.y, a.y*b.x - a.x*b.y}; } // a*conj(b)
__device__ inline cf cscale(cf a, float s){ return {a.x*s, a.y*s}; }
__device__ inline cf csqrtf_c(cf z){
    float r = sqrtf(z.x*z.x + z.y*z.y);
    float u = sqrtf(fmaxf(0.5f*(r + z.x), 0.0f));
    float v = sqrtf(fmaxf(0.5f*(r - z.x), 0.0f));
    if (z.y < 0.0f) v = -v;
    return {u, v};
}

__global__ __launch_bounds__(640)
void esprit_kernel(const float* __restrict__ x, float* __restrict__ out)
{
    __shared__ __align__(16) float xw[XW_SIZE];
    __shared__ float XsR[NK][NTT][NMIC], XsI[NK][NTT][NMIC];

    const int tid = threadIdx.x;

    // ---- stage 0: coalesced float4 staging + window, into skewed LDS ------
    // xw(t,n) = sin(pi*n/512) * x[XBASE + t*256 + n][:]   (2048 float4 total)
    for (int e = tid; e < NTT * NFFT; e += 640) {
        int t = e >> 9;
        int n = e & 511;
        float4 v = ((const float4*)x)[XBASE + t * 256 + n];
        float w = __sinf((float)n * (PI_F / 512.0f));      // sqrt-hann
        v.x *= w; v.y *= w; v.z *= w; v.w *= w;
        *(float4*)&xw[t * FRM_STRIDE + (n >> 6) * CHK_STRIDE + (n & 63) * 4] = v;
    }
    __syncthreads();

    // ---- stage 1: 76 (k,t) bins x 8 sample-parts, rotation recurrence -----
    if (tid < 608) {
        const int bin = tid >> 3;        // 0..75
        const int p   = tid & 7;         // part: samples [64p, 64p+64)
        const int kk  = bin >> 2;        // 0..18
        const int t   = bin & 3;
        const int k   = KLO + kk;
        const int n0  = p << 6;
        const int j0  = (k * n0) & 511;  // exact k*n0 mod 512

        float cr, ci, wc, ws;
        __sincosf((float)j0 * (-2.0f * PI_F / 512.0f), &ci, &cr);  // e^{-2pi i j0/512}
        __sincosf((float)k  * (-2.0f * PI_F / 512.0f), &ws, &wc);  // step e^{-2pi i k/512}

        float re0=0,re1=0,re2=0,re3=0, im0=0,im1=0,im2=0,im3=0;
        const int boff = t * FRM_STRIDE + p * CHK_STRIDE;   // 16B-aligned
        #pragma unroll 8
        for (int i = 0; i < 64; ++i) {
            float4 v = *(const float4*)&xw[boff + 4*i];
            re0 = fmaf(v.x, cr, re0); im0 = fmaf(v.x, ci, im0);
            re1 = fmaf(v.y, cr, re1); im1 = fmaf(v.y, ci, im1);
            re2 = fmaf(v.z, cr, re2); im2 = fmaf(v.z, ci, im2);
            re3 = fmaf(v.w, cr, re3); im3 = fmaf(v.w, ci, im3);
            float nr = fmaf(cr, wc, -(ci * ws));
            float ni = fmaf(cr, ws,  (ci * wc));
            cr = nr; ci = ni;
        }
        // reduce the 8 parts (contiguous lanes)
        #pragma unroll
        for (int mask = 1; mask < 8; mask <<= 1) {
            re0 += __shfl_xor(re0, mask); im0 += __shfl_xor(im0, mask);
            re1 += __shfl_xor(re1, mask); im1 += __shfl_xor(im1, mask);
            re2 += __shfl_xor(re2, mask); im2 += __shfl_xor(im2, mask);
            re3 += __shfl_xor(re3, mask); im3 += __shfl_xor(im3, mask);
        }
        if (p == 0) {
            XsR[kk][t][0] = re0; XsI[kk][t][0] = im0;
            XsR[kk][t][1] = re1; XsI[kk][t][1] = im1;
            XsR[kk][t][2] = re2; XsI[kk][t][2] = im2;
            XsR[kk][t][3] = re3; XsI[kk][t][3] = im3;
        }
    }
    __syncthreads();

    // ---- stage 2: per-frequency ESPRIT on wave 0, then in-wave mean -------
    float asum = 0.0f;
    if (tid < 64) {
        if (tid < NK) {
            cf Xm[NMIC][NTT];
            for (int m = 0; m < NMIC; ++m)
                for (int t = 0; t < NTT; ++t)
                    Xm[m][t] = { XsR[tid][t][m], XsI[tid][t][m] };

            // R = (1/4) Xs Xs^H
            cf R[4][4];
            for (int i = 0; i < 4; ++i)
                for (int j = 0; j < 4; ++j) {
                    cf acc = {0.f, 0.f};
                    for (int t = 0; t < 4; ++t) acc = cadd(acc, cmulc(Xm[i][t], Xm[j][t]));
                    R[i][j] = cscale(acc, 0.25f);
                }

            // one orthogonal-iteration step -> dominant 2-D subspace
            // (phi eigvals similarity-invariant; lam3/lam2 ~ 1e-8 at -80 dB
            //  noise; validated absmax 0.0 in rounds 6/7)
            cf Q[4][2], Y[4][2];
            for (int i = 0; i < 4; ++i) { Y[i][0] = R[i][0]; Y[i][1] = R[i][1]; }
            float nrm0 = 0.f;
            for (int i = 0; i < 4; ++i) nrm0 += Y[i][0].x*Y[i][0].x + Y[i][0].y*Y[i][0].y;
            float in0 = __builtin_amdgcn_rsqf(nrm0);
            for (int i = 0; i < 4; ++i) Q[i][0] = cscale(Y[i][0], in0);
            cf pr = {0.f, 0.f};
            for (int i = 0; i < 4; ++i) pr = cadd(pr, cmulc(Y[i][1], Q[i][0]));  // Q0^H Y1
            for (int i = 0; i < 4; ++i) Q[i][1] = csub(Y[i][1], cmul(pr, Q[i][0]));
            float nrm1 = 0.f;
            for (int i = 0; i < 4; ++i) nrm1 += Q[i][1].x*Q[i][1].x + Q[i][1].y*Q[i][1].y;
            float in1 = __builtin_amdgcn_rsqf(nrm1);
            for (int i = 0; i < 4; ++i) Q[i][1] = cscale(Q[i][1], in1);

            // A = s0^H s0 (Hermitian), B = s0^H s1 ; s0 = rows 0..2, s1 = rows 1..3
            float a00 = 0.f, a11 = 0.f;
            cf a01 = {0.f, 0.f};
            cf B[2][2] = { { {0,0}, {0,0} }, { {0,0}, {0,0} } };
            for (int i = 0; i < 3; ++i) {
                a00 += Q[i][0].x*Q[i][0].x + Q[i][0].y*Q[i][0].y;
                a11 += Q[i][1].x*Q[i][1].x + Q[i][1].y*Q[i][1].y;
                a01 = cadd(a01, cmulc(Q[i][1], Q[i][0]));      // conj(Q0)*Q1
                for (int r2 = 0; r2 < 2; ++r2)
                    for (int c2 = 0; c2 < 2; ++c2)
                        B[r2][c2] = cadd(B[r2][c2], cmulc(Q[i+1][c2], Q[i][r2]));
            }
            float detA = a00*a11 - (a01.x*a01.x + a01.y*a01.y);
            float inv  = __builtin_amdgcn_rcpf(detA);
            cf na01  = { -a01.x, -a01.y };
            cf na01c = { -a01.x,  a01.y };
            cf phi00 = cscale(cadd(cscale(B[0][0], a11), cmul(na01,  B[1][0])), inv);
            cf phi01 = cscale(cadd(cscale(B[0][1], a11), cmul(na01,  B[1][1])), inv);
            cf phi10 = cscale(cadd(cmul(na01c, B[0][0]), cscale(B[1][0], a00)), inv);
            cf phi11 = cscale(cadd(cmul(na01c, B[0][1]), cscale(B[1][1], a00)), inv);

            cf tr = cadd(phi00, phi11);
            cf dt = csub(cmul(phi00, phi11), cmul(phi01, phi10));
            cf d2 = csub(cmul(tr, tr), cscale(dt, 4.0f));
            cf disc = csqrtf_c(d2);
            cf lam0 = cscale(cadd(tr, disc), 0.5f);
            cf lam1 = cscale(csub(tr, disc), 0.5f);

            float f     = 31.25f * (float)(KLO + tid);
            float scale = 343.0f / (2.0f * PI_F * f * 0.08f);
            float ph0 = atan2f(lam0.y, lam0.x);
            float ph1 = atan2f(lam1.y, lam1.x);
            float g0 = fminf(fmaxf(ph0 * scale, -1.0f), 1.0f);
            float g1 = fminf(fmaxf(ph1 * scale, -1.0f), 1.0f);
            asum = (asinf(g0) + asinf(g1)) * (180.0f / PI_F);
        }
        // in-wave mean over the 19 bins (lanes >= 19 contribute 0)
        #pragma unroll
        for (int mask = 32; mask >= 1; mask >>= 1)
            asum += __shfl_xor(asum, mask);
        if (tid == 0) out[0] = asum * (1.0f / 38.0f);
    }
}

extern "C" void kernel_launch(void* const* d_in, const int* in_sizes, int n_in,
                              void* d_out, int out_size, void* d_ws, size_t ws_size,
                              hipStream_t stream)
{
    const float* x = (const float*)d_in[0];
    float* out = (float*)d_out;
    esprit_kernel<<<1, 640, 0, stream>>>(x, out);
}